// Round 1
// baseline (365.833 us; speedup 1.0000x reference)
//
#include <hip/hip_runtime.h>

// RF-scale (KS=3, RATIO=0.5, reflect pad 1): out[b,c,3h+i,3w+j] =
//   0.25*(x[r0][c0]+x[r0][c1]+x[r1][c0]+x[r1][c1])
// with (r0,r1): i==0 -> (refl(h-1), h); i==1 -> (h,h); i==2 -> (h, refl(h+1))
// and same pattern for columns with j. refl(-1)=1, refl(128)=126.
//
// One thread = 12 consecutive output cols (4 input cols): 2x float4 input
// loads + 4 reflect-edge scalar loads, 3x float4 coalesced stores.

namespace {

constexpr int H  = 128, W  = 128;
constexpr int HO = 384, WO = 384;

__global__ __launch_bounds__(256) void rf_scale_kernel(const float* __restrict__ x,
                                                       float* __restrict__ out,
                                                       int nthreads) {
    int tid = blockIdx.x * 256 + threadIdx.x;
    if (tid >= nthreads) return;

    int g   = tid & 31;      // column group: output cols [12g, 12g+12), input cols [4g, 4g+4)
    int rem = tid >> 5;
    int ho  = rem % HO;      // output row
    int bc  = rem / HO;      // fused batch*channel

    int h = ho / 3;          // compiler emits magic-mul
    int i = ho - h * 3;

    int r0 = h, r1 = h;
    if (i == 0)      r0 = (h == 0)     ? 1     : h - 1;   // refl(h-1)
    else if (i == 2) r1 = (h == H - 1) ? H - 2 : h + 1;   // refl(h+1)

    const float* base = x + (size_t)bc * (H * W);
    const float* row0 = base + r0 * W;
    const float* row1 = base + r1 * W;

    int wb = g << 2;                             // first input col
    int cm = (wb == 0)     ? 1     : wb - 1;     // refl(wb-1)
    int cp = (wb == W - 4) ? W - 2 : wb + 4;     // refl(wb+4)

    float4 a0 = *(const float4*)(row0 + wb);
    float4 a1 = *(const float4*)(row1 + wb);
    float  m  = row0[cm] + row1[cm];
    float  p  = row0[cp] + row1[cp];

    // row-folded values R[c] = x[r0][c] + x[r1][c]
    float R0 = m;
    float R1 = a0.x + a1.x;
    float R2 = a0.y + a1.y;
    float R3 = a0.z + a1.z;
    float R4 = a0.w + a1.w;
    float R5 = p;

    float e01 = 0.25f * (R0 + R1);
    float e12 = 0.25f * (R1 + R2);
    float e23 = 0.25f * (R2 + R3);
    float e34 = 0.25f * (R3 + R4);
    float e45 = 0.25f * (R4 + R5);

    // 12 outputs in order: (t=0..3) x (j=0..2)
    float4 o0 = make_float4(e01,       0.5f * R1, e12,       e12);
    float4 o1 = make_float4(0.5f * R2, e23,       e23,       0.5f * R3);
    float4 o2 = make_float4(e34,       e34,       0.5f * R4, e45);

    float* op = out + (size_t)bc * (HO * WO) + (size_t)ho * WO + wb * 3;
    *(float4*)(op)     = o0;
    *(float4*)(op + 4) = o1;
    *(float4*)(op + 8) = o2;
}

} // namespace

extern "C" void kernel_launch(void* const* d_in, const int* in_sizes, int n_in,
                              void* d_out, int out_size, void* d_ws, size_t ws_size,
                              hipStream_t stream) {
    const float* x = (const float*)d_in[0];
    float* out = (float*)d_out;

    int nbc = in_sizes[0] / (H * W);         // 8*64 = 512
    int nthreads = nbc * HO * 32;            // one thread per 12 output cols
    int blocks = (nthreads + 255) / 256;

    rf_scale_kernel<<<blocks, 256, 0, stream>>>(x, out, nthreads);
}

// Round 2
// 330.777 us; speedup vs baseline: 1.1060x; 1.1060x over previous
//
#include <hip/hip_runtime.h>

// RF-scale (KS=3, RATIO=0.5, reflect pad 1): out[b,c,3h+i,3w+j] =
//   0.25*(x[r0][c0]+x[r0][c1]+x[r1][c0]+x[r1][c1])
// with (r0,r1): i==0 -> (refl(h-1), h); i==1 -> (h,h); i==2 -> (h, refl(h+1))
// and same for columns with j. refl(-1)=1, refl(128)=126.
//
// Round-2 change: stores were 48-B-stride per lane (3x transaction
// amplification on the write-dominated path). Now each block computes a
// contiguous 12 KB output region (8 rows x 384 cols of one bc) into LDS,
// then writes it back with lane-contiguous float4 stores.

namespace {

constexpr int H  = 128, W  = 128;
constexpr int HO = 384, WO = 384;

__global__ __launch_bounds__(256) void rf_scale_kernel(const float* __restrict__ x,
                                                       float* __restrict__ out) {
    __shared__ float lds[8 * WO];          // 12 KB: 8 output rows x 384 cols

    const int tid    = threadIdx.x;
    const int g      = tid & 31;           // column group: output cols [12g,12g+12)
    const int lr     = tid >> 5;           // local output row 0..7
    const int rowgrp = blockIdx.x;         // 48 row-groups of 8 output rows
    const int bc     = blockIdx.y;         // fused batch*channel

    const int ho = rowgrp * 8 + lr;        // output row 0..383
    const int h  = ho / 3;                 // magic-mul
    const int i  = ho - h * 3;

    int r0 = h, r1 = h;
    if (i == 0)      r0 = (h == 0)     ? 1     : h - 1;   // refl(h-1)
    else if (i == 2) r1 = (h == H - 1) ? H - 2 : h + 1;   // refl(h+1)

    const float* base = x + (size_t)bc * (H * W);
    const float* row0 = base + r0 * W;
    const float* row1 = base + r1 * W;

    const int wb = g << 2;                            // first input col
    const int cm = (wb == 0)     ? 1     : wb - 1;    // refl(wb-1)
    const int cp = (wb == W - 4) ? W - 2 : wb + 4;    // refl(wb+4)

    float4 a0 = *(const float4*)(row0 + wb);
    float4 a1 = *(const float4*)(row1 + wb);
    float  m  = row0[cm] + row1[cm];
    float  p  = row0[cp] + row1[cp];

    // row-folded values R[c] = x[r0][c] + x[r1][c]
    float R0 = m;
    float R1 = a0.x + a1.x;
    float R2 = a0.y + a1.y;
    float R3 = a0.z + a1.z;
    float R4 = a0.w + a1.w;
    float R5 = p;

    float e01 = 0.25f * (R0 + R1);
    float e12 = 0.25f * (R1 + R2);
    float e23 = 0.25f * (R2 + R3);
    float e34 = 0.25f * (R3 + R4);
    float e45 = 0.25f * (R4 + R5);

    // 12 outputs in order: (t=0..3) x (j=0..2)
    float4 o0 = make_float4(e01,       0.5f * R1, e12,       e12);
    float4 o1 = make_float4(0.5f * R2, e23,       e23,       0.5f * R3);
    float4 o2 = make_float4(e34,       e34,       0.5f * R4, e45);

    // stage into LDS at the output layout (conflict-free: 8 consecutive
    // lanes at 48-B stride cover all 32 banks disjointly)
    float* lp = lds + lr * WO + g * 12;
    ((float4*)lp)[0] = o0;
    ((float4*)lp)[1] = o1;
    ((float4*)lp)[2] = o2;

    __syncthreads();

    // block's output region is contiguous: rows [rowgrp*8, rowgrp*8+8) of bc
    const float4* ls = (const float4*)lds;
    float4* op = (float4*)(out + ((size_t)bc * HO + (size_t)rowgrp * 8) * WO);
    op[tid]       = ls[tid];
    op[tid + 256] = ls[tid + 256];
    op[tid + 512] = ls[tid + 512];
}

} // namespace

extern "C" void kernel_launch(void* const* d_in, const int* in_sizes, int n_in,
                              void* d_out, int out_size, void* d_ws, size_t ws_size,
                              hipStream_t stream) {
    const float* x = (const float*)d_in[0];
    float* out = (float*)d_out;

    int nbc = in_sizes[0] / (H * W);       // 8*64 = 512
    dim3 grid(HO / 8, nbc);                // 48 row-groups x 512 bc
    rf_scale_kernel<<<grid, 256, 0, stream>>>(x, out);
}

// Round 3
// 321.768 us; speedup vs baseline: 1.1369x; 1.0280x over previous
//
#include <hip/hip_runtime.h>

// RF-scale (KS=3, RATIO=0.5, reflect pad 1): out[b,c,3h+i,3w+j] =
//   0.25*(x[r0][c0]+x[r0][c1]+x[r1][c0]+x[r1][c1])
// with (r0,r1): i==0 -> (refl(h-1), h); i==1 -> (h,h); i==2 -> (h, refl(h+1))
// and same for columns with j. refl(-1)=1, refl(128)=126.
//
// Round-3 change: the 4 reflect-edge scalar loads per thread were redundant —
// row[wb-1] / row[wb+4] live in the adjacent lane's registers, and the
// column-reflect cases (g==0 -> col 1, g==31 -> col 126) are the thread's OWN
// R2/R3. Replaced with __shfl_up/__shfl_down on the row-folded values:
// 2 VMEM loads/thread instead of 6. Wave-boundary shuffle contamination
// (lanes 32 and 31) lands exactly on the g==0 / g==31 reflect-override lanes.

namespace {

constexpr int H  = 128, W  = 128;
constexpr int HO = 384, WO = 384;

__global__ __launch_bounds__(256) void rf_scale_kernel(const float* __restrict__ x,
                                                       float* __restrict__ out) {
    __shared__ float lds[8 * WO];          // 12 KB: 8 output rows x 384 cols

    const int tid    = threadIdx.x;
    const int g      = tid & 31;           // column group: output cols [12g,12g+12)
    const int lr     = tid >> 5;           // local output row 0..7
    const int rowgrp = blockIdx.x;         // 48 row-groups of 8 output rows
    const int bc     = blockIdx.y;         // fused batch*channel

    const int ho = rowgrp * 8 + lr;        // output row 0..383
    const int h  = ho / 3;                 // magic-mul
    const int i  = ho - h * 3;

    int r0 = h, r1 = h;
    if (i == 0)      r0 = (h == 0)     ? 1     : h - 1;   // refl(h-1)
    else if (i == 2) r1 = (h == H - 1) ? H - 2 : h + 1;   // refl(h+1)

    const float* base = x + (size_t)bc * (H * W);
    const int wb = g << 2;                 // first input col

    float4 a0 = *(const float4*)(base + r0 * W + wb);
    float4 a1 = *(const float4*)(base + r1 * W + wb);

    // row-folded values R[c] = x[r0][c] + x[r1][c] for c = wb..wb+3
    float R1 = a0.x + a1.x;
    float R2 = a0.y + a1.y;
    float R3 = a0.z + a1.z;
    float R4 = a0.w + a1.w;

    // neighbors via intra-wave shuffle; reflect overrides at column edges.
    // lane 32's shfl_up and lane 31's shfl_down cross the row boundary, but
    // those lanes are exactly g==0 / g==31 where the override applies.
    float Rm = __shfl_up(R4, 1);           // fold at col wb-1 (from lane g-1)
    float Rp = __shfl_down(R1, 1);         // fold at col wb+4 (from lane g+1)
    float R0 = (g == 0)  ? R2 : Rm;        // refl(-1) = 1  -> own R2
    float R5 = (g == 31) ? R3 : Rp;        // refl(128)=126 -> own R3

    float e01 = 0.25f * (R0 + R1);
    float e12 = 0.25f * (R1 + R2);
    float e23 = 0.25f * (R2 + R3);
    float e34 = 0.25f * (R3 + R4);
    float e45 = 0.25f * (R4 + R5);

    // 12 outputs in order: (t=0..3) x (j=0..2)
    float4 o0 = make_float4(e01,       0.5f * R1, e12,       e12);
    float4 o1 = make_float4(0.5f * R2, e23,       e23,       0.5f * R3);
    float4 o2 = make_float4(e34,       e34,       0.5f * R4, e45);

    // stage into LDS at the output layout (8 consecutive lanes at 48-B
    // stride cover all 32 banks disjointly -> conflict-free)
    float* lp = lds + lr * WO + g * 12;
    ((float4*)lp)[0] = o0;
    ((float4*)lp)[1] = o1;
    ((float4*)lp)[2] = o2;

    __syncthreads();

    // block's output region is contiguous: rows [rowgrp*8, rowgrp*8+8) of bc
    const float4* ls = (const float4*)lds;
    float4* op = (float4*)(out + ((size_t)bc * HO + (size_t)rowgrp * 8) * WO);
    op[tid]       = ls[tid];
    op[tid + 256] = ls[tid + 256];
    op[tid + 512] = ls[tid + 512];
}

} // namespace

extern "C" void kernel_launch(void* const* d_in, const int* in_sizes, int n_in,
                              void* d_out, int out_size, void* d_ws, size_t ws_size,
                              hipStream_t stream) {
    const float* x = (const float*)d_in[0];
    float* out = (float*)d_out;

    int nbc = in_sizes[0] / (H * W);       // 8*64 = 512
    dim3 grid(HO / 8, nbc);                // 48 row-groups x 512 bc
    rf_scale_kernel<<<grid, 256, 0, stream>>>(x, out);
}

// Round 5
// 311.953 us; speedup vs baseline: 1.1727x; 1.0315x over previous
//
#include <hip/hip_runtime.h>

// RF-scale (KS=3, RATIO=0.5, reflect pad 1): out[b,c,3h+i,3w+j] =
//   0.25*(x[r0][c0]+x[r0][c1]+x[r1][c0]+x[r1][c1])
// with (r0,r1): i==0 -> (refl(h-1), h); i==1 -> (h,h); i==2 -> (h, refl(h+1))
// and same for columns with j. refl(-1)=1, refl(128)=126.
//
// Round-5 = round-4 with the nontemporal-store compile fix (clang
// ext_vector_type instead of HIP_vector_type float4):
//  * Nontemporal (nt) stores for the 302 MB output stream — keeps the 32 MB
//    input resident in the 32 MB aggregate L2 instead of thrashing it.
//  * No __syncthreads(): each wave's 2 output rows are wave-private in LDS
//    (it reads back only what it wrote), so waves stream independently.

namespace {

constexpr int H  = 128, W  = 128;
constexpr int HO = 384, WO = 384;

typedef float f32x4 __attribute__((ext_vector_type(4)));

__global__ __launch_bounds__(256) void rf_scale_kernel(const float* __restrict__ x,
                                                       float* __restrict__ out) {
    __shared__ float lds[8 * WO];          // 12 KB: 8 output rows x 384 cols

    const int tid    = threadIdx.x;
    const int g      = tid & 31;           // column group: output cols [12g,12g+12)
    const int lr     = tid >> 5;           // local output row 0..7 (2 per wave)
    const int rowgrp = blockIdx.x;         // 48 row-groups of 8 output rows
    const int bc     = blockIdx.y;         // fused batch*channel

    const int ho = rowgrp * 8 + lr;        // output row 0..383
    const int h  = ho / 3;                 // magic-mul
    const int i  = ho - h * 3;

    int r0 = h, r1 = h;
    if (i == 0)      r0 = (h == 0)     ? 1     : h - 1;   // refl(h-1)
    else if (i == 2) r1 = (h == H - 1) ? H - 2 : h + 1;   // refl(h+1)

    const float* base = x + (size_t)bc * (H * W);
    const int wb = g << 2;                 // first input col

    f32x4 a0 = *(const f32x4*)(base + r0 * W + wb);
    f32x4 a1 = *(const f32x4*)(base + r1 * W + wb);

    // row-folded values R[c] = x[r0][c] + x[r1][c] for c = wb..wb+3
    float R1 = a0.x + a1.x;
    float R2 = a0.y + a1.y;
    float R3 = a0.z + a1.z;
    float R4 = a0.w + a1.w;

    // neighbors via intra-wave shuffle; reflect overrides at column edges.
    // half-wave-boundary contamination (lanes 32 / 31) lands exactly on the
    // g==0 / g==31 reflect-override lanes.
    float Rm = __shfl_up(R4, 1);           // fold at col wb-1 (from lane g-1)
    float Rp = __shfl_down(R1, 1);         // fold at col wb+4 (from lane g+1)
    float R0 = (g == 0)  ? R2 : Rm;        // refl(-1) = 1  -> own R2
    float R5 = (g == 31) ? R3 : Rp;        // refl(128)=126 -> own R3

    float e01 = 0.25f * (R0 + R1);
    float e12 = 0.25f * (R1 + R2);
    float e23 = 0.25f * (R2 + R3);
    float e34 = 0.25f * (R3 + R4);
    float e45 = 0.25f * (R4 + R5);

    // 12 outputs in order: (t=0..3) x (j=0..2)
    f32x4 o0 = {e01,       0.5f * R1, e12,       e12      };
    f32x4 o1 = {0.5f * R2, e23,       e23,       0.5f * R3};
    f32x4 o2 = {e34,       e34,       0.5f * R4, e45      };

    // stage into LDS at the output layout (8 consecutive lanes at 48-B
    // stride cover all 32 banks disjointly -> conflict-free)
    float* lp = lds + lr * WO + g * 12;
    ((f32x4*)lp)[0] = o0;
    ((f32x4*)lp)[1] = o1;
    ((f32x4*)lp)[2] = o2;

    // NO __syncthreads(): each wave reads back only its own 2 rows
    // (wave-private 3 KB slice); same-wave DS ordering is guaranteed.
    const int wv = tid >> 6;               // wave 0..3
    const int ln = tid & 63;
    const int b0 = wv * 192 + ln;          // wave slice: f32x4 [192w, 192w+192)

    const f32x4* ls = (const f32x4*)lds;
    f32x4* op = (f32x4*)(out + ((size_t)bc * HO + (size_t)rowgrp * 8) * WO);
    __builtin_nontemporal_store(ls[b0],       &op[b0]);
    __builtin_nontemporal_store(ls[b0 + 64],  &op[b0 + 64]);
    __builtin_nontemporal_store(ls[b0 + 128], &op[b0 + 128]);
}

} // namespace

extern "C" void kernel_launch(void* const* d_in, const int* in_sizes, int n_in,
                              void* d_out, int out_size, void* d_ws, size_t ws_size,
                              hipStream_t stream) {
    const float* x = (const float*)d_in[0];
    float* out = (float*)d_out;

    int nbc = in_sizes[0] / (H * W);       // 8*64 = 512
    dim3 grid(HO / 8, nbc);                // 48 row-groups x 512 bc
    rf_scale_kernel<<<grid, 256, 0, stream>>>(x, out);
}

// Round 6
// 310.006 us; speedup vs baseline: 1.1801x; 1.0063x over previous
//
#include <hip/hip_runtime.h>

// RF-scale (KS=3, RATIO=0.5, reflect pad 1): out[b,c,3h+i,3w+j] =
//   0.25*(x[r0][c0]+x[r0][c1]+x[r1][c0]+x[r1][c1]),
// rows: i==0 -> (refl(h-1),h); i==1 -> (h,h); i==2 -> (h,refl(h+1)); cols same
// pattern with j. refl(-1)=1, refl(128)=126.
//
// Round-6: one thread = one input row x 4 input cols -> all 3 output rows
// (36 outputs). Loads rows refl(h-1), h, refl(h+1) once (3 loads per 36
// outputs vs 6 before), 3x L1 reuse in-block, no div for ho/3, 3x fewer
// waves. Store path unchanged: LDS-staged wave-private slices, nontemporal
// lane-contiguous float4 streams, no __syncthreads.

namespace {

constexpr int H  = 128, W  = 128;
constexpr int HO = 384, WO = 384;

typedef float f32x4 __attribute__((ext_vector_type(4)));

// Writes 12 consecutive output floats for one output row given the fold
// values S1..S4 (cols wb..wb+3) and edge neighbors S0 (col wb-1), S5 (wb+4).
// Layout (t=0..3)x(j=0..2): [e01, wc*S1, e12, e12, wc*S2, e23, e23, wc*S3,
// e34, e34, wc*S4, e45] with e_xy = we*(Sx+Sy).
__device__ __forceinline__ void emit12(float* lp, float S0, float S1, float S2,
                                       float S3, float S4, float S5,
                                       float we, float wc) {
    float e01 = we * (S0 + S1);
    float e12 = we * (S1 + S2);
    float e23 = we * (S2 + S3);
    float e34 = we * (S3 + S4);
    float e45 = we * (S4 + S5);
    f32x4 o0 = {e01,     wc * S1, e12,     e12    };
    f32x4 o1 = {wc * S2, e23,     e23,     wc * S3};
    f32x4 o2 = {e34,     e34,     wc * S4, e45    };
    ((f32x4*)lp)[0] = o0;
    ((f32x4*)lp)[1] = o1;
    ((f32x4*)lp)[2] = o2;
}

__global__ __launch_bounds__(256) void rf_scale_kernel(const float* __restrict__ x,
                                                       float* __restrict__ out) {
    __shared__ float lds[24 * WO];         // 36 KB: 24 output rows x 384 cols

    const int tid = threadIdx.x;
    const int g   = tid & 31;              // column group: input cols [4g,4g+4)
    const int hl  = tid >> 5;              // local input row 0..7
    const int bx  = blockIdx.x;            // 16 row-groups of 8 input rows
    const int bc  = blockIdx.y;            // fused batch*channel

    const int h  = bx * 8 + hl;            // input row
    const int rm = (h == 0)     ? 1     : h - 1;   // refl(h-1)
    const int rp = (h == H - 1) ? H - 2 : h + 1;   // refl(h+1)

    const float* base = x + (size_t)bc * (H * W);
    const int wb = g << 2;

    f32x4 xm = *(const f32x4*)(base + rm * W + wb);
    f32x4 x0 = *(const f32x4*)(base + h  * W + wb);
    f32x4 xp = *(const f32x4*)(base + rp * W + wb);

    float* lp = lds + (3 * hl) * WO + g * 12;

    // ---- output row 3h (fold A = xm + x0), weights 0.25 / 0.5 ----
    {
        float A1 = xm.x + x0.x, A2 = xm.y + x0.y, A3 = xm.z + x0.z, A4 = xm.w + x0.w;
        // neighbor folds via shuffle; half-wave boundary contamination lands
        // exactly on the g==0 / g==31 reflect-override lanes.
        float Am = __shfl_up(A4, 1);
        float Ap = __shfl_down(A1, 1);
        float A0 = (g == 0)  ? A2 : Am;    // refl(-1)=1   -> own col 1
        float A5 = (g == 31) ? A3 : Ap;    // refl(128)=126 -> own col 126
        emit12(lp, A0, A1, A2, A3, A4, A5, 0.25f, 0.5f);
    }
    // ---- output row 3h+1 (exact row, S = x0), weights 0.5 / 1.0 ----
    {
        float Bm = __shfl_up(x0.w, 1);
        float Bp = __shfl_down(x0.x, 1);
        float B0 = (g == 0)  ? x0.y : Bm;
        float B5 = (g == 31) ? x0.z : Bp;
        emit12(lp + WO, B0, x0.x, x0.y, x0.z, x0.w, B5, 0.5f, 1.0f);
    }
    // ---- output row 3h+2 (fold C = x0 + xp), weights 0.25 / 0.5 ----
    {
        float C1 = x0.x + xp.x, C2 = x0.y + xp.y, C3 = x0.z + xp.z, C4 = x0.w + xp.w;
        float Cm = __shfl_up(C4, 1);
        float Cp = __shfl_down(C1, 1);
        float C0 = (g == 0)  ? C2 : Cm;
        float C5 = (g == 31) ? C3 : Cp;
        emit12(lp + 2 * WO, C0, C1, C2, C3, C4, C5, 0.25f, 0.5f);
    }

    // NO __syncthreads(): wave wv wrote local output rows 6wv..6wv+5
    // (hl in {2wv, 2wv+1}) and reads back exactly that 9-KB slice.
    const int wv = tid >> 6;               // wave 0..3
    const int ln = tid & 63;
    const int b0 = wv * 576 + ln;          // f32x4 slice [576wv, 576wv+576)

    const f32x4* ls = (const f32x4*)lds;
    f32x4* op = (f32x4*)(out + ((size_t)bc * HO + (size_t)bx * 24) * WO);
#pragma unroll
    for (int k = 0; k < 9; ++k)
        __builtin_nontemporal_store(ls[b0 + 64 * k], &op[b0 + 64 * k]);
}

} // namespace

extern "C" void kernel_launch(void* const* d_in, const int* in_sizes, int n_in,
                              void* d_out, int out_size, void* d_ws, size_t ws_size,
                              hipStream_t stream) {
    const float* x = (const float*)d_in[0];
    float* out = (float*)d_out;

    int nbc = in_sizes[0] / (H * W);       // 8*64 = 512
    dim3 grid(H / 8, nbc);                 // 16 row-groups x 512 bc
    rf_scale_kernel<<<grid, 256, 0, stream>>>(x, out);
}